// Round 2
// baseline (1403.076 us; speedup 1.0000x reference)
//
#include <hip/hip_runtime.h>
#include <cstdint>
#include <cstddef>

#define BB 256
#define NN 1000
#define DD 512
#define HH 8

// ============================================================================
// K1: state[b,e] = dec_in[b,:] @ W_fc + pool[b,:] @ W_fc1
// ============================================================================
__global__ __launch_bounds__(256) void k_state(
    const float* __restrict__ X, const float* __restrict__ pool,
    const float* __restrict__ cap, const float* __restrict__ Wfc,
    const float* __restrict__ Wfc1, float* __restrict__ state) {
  __shared__ float dec_lds[8][DD];
  __shared__ float pool_lds[8][DD];
  __shared__ float cap_lds[8];
  const int t = threadIdx.x;
  const int b0 = blockIdx.x * 8;
  for (int i = t; i < 8 * 128; i += 256) {
    int r = i >> 7, c4 = i & 127;
    ((float4*)dec_lds[r])[c4]  = ((const float4*)(X + (size_t)(b0 + r) * NN * DD))[c4];
    ((float4*)pool_lds[r])[c4] = ((const float4*)(pool + (size_t)(b0 + r) * DD))[c4];
  }
  if (t < 8) cap_lds[t] = cap[b0 + t];
  __syncthreads();
  const int e = blockIdx.y * 64 + (t & 63);
  const int g = t >> 6;
  const int r0 = g * 2, r1 = r0 + 1;
  float a0 = 0.f, a1 = 0.f;
  for (int d = 0; d < DD; ++d) {
    float w1 = Wfc[(size_t)d * DD + e];
    float w2 = Wfc1[(size_t)d * DD + e];
    a0 = fmaf(dec_lds[r0][d], w1, a0); a0 = fmaf(pool_lds[r0][d], w2, a0);
    a1 = fmaf(dec_lds[r1][d], w1, a1); a1 = fmaf(pool_lds[r1][d], w2, a1);
  }
  float wc = Wfc[(size_t)DD * DD + e];
  a0 += cap_lds[r0] * wc;
  a1 += cap_lds[r1] * wc;
  state[(size_t)(b0 + r0) * DD + e] = a0;
  state[(size_t)(b0 + r1) * DD + e] = a1;
}

// ============================================================================
// K2: Qt[b,h,d] = (1/8) * sum_hd (state[b,:]@Wq)[h*64+hd] * Wk[d, h*64+hd]
// ============================================================================
__global__ __launch_bounds__(256) void k_qt(
    const float* __restrict__ state, const float* __restrict__ Wq,
    const float* __restrict__ Wk, float* __restrict__ Qt) {
  __shared__ float s_lds[8][DD];
  __shared__ float q_lds[8][64];
  __shared__ float wk_lds[64][65];
  const int t = threadIdx.x;
  const int b0 = blockIdx.x * 8;
  const int h = blockIdx.y;
  for (int i = t; i < 8 * 128; i += 256) {
    int r = i >> 7, c4 = i & 127;
    ((float4*)s_lds[r])[c4] = ((const float4*)(state + (size_t)(b0 + r) * DD))[c4];
  }
  __syncthreads();
  const int hd = t & 63;
  const int g = t >> 6;
  const int r0 = g * 2, r1 = r0 + 1;
  {
    float a0 = 0.f, a1 = 0.f;
    for (int e = 0; e < DD; ++e) {
      float w = Wq[(size_t)e * DD + h * 64 + hd];
      a0 = fmaf(s_lds[r0][e], w, a0);
      a1 = fmaf(s_lds[r1][e], w, a1);
    }
    q_lds[r0][hd] = a0;
    q_lds[r1][hd] = a1;
  }
  const float norm = 0.125f;  // 1/sqrt(64)
  for (int dc = 0; dc < DD; dc += 64) {
    __syncthreads();
    for (int i = t; i < 64 * 16; i += 256) {
      int row = i >> 4, c4 = i & 15;
      float4 wv = ((const float4*)(Wk + (size_t)(dc + row) * DD + h * 64))[c4];
      wk_lds[row][c4 * 4 + 0] = wv.x; wk_lds[row][c4 * 4 + 1] = wv.y;
      wk_lds[row][c4 * 4 + 2] = wv.z; wk_lds[row][c4 * 4 + 3] = wv.w;
    }
    __syncthreads();
    const int dl = t & 63;
    float a0 = 0.f, a1 = 0.f;
    for (int k = 0; k < 64; ++k) {
      float w = wk_lds[dl][k];
      a0 = fmaf(q_lds[r0][k], w, a0);
      a1 = fmaf(q_lds[r1][k], w, a1);
    }
    Qt[((size_t)(b0 + r0) * HH + h) * DD + dc + dl] = norm * a0;
    Qt[((size_t)(b0 + r1) * HH + h) * DD + dc + dl] = norm * a1;
  }
}

// ============================================================================
// K3: split-N flash attention pass. grid (3, B) -> 3 blocks/CU exactly.
// Each block: tiles [21s, 21s+21), online softmax, writes UNNORMALIZED ctx
// partial + (m, l) to ws. Merge happens in k_pre_merge.
// ============================================================================
__global__ __launch_bounds__(256, 3) void k_attn(
    const float* __restrict__ X, const int* __restrict__ mask,
    const float* __restrict__ Qt, float* __restrict__ ctx_part,
    float* __restrict__ ml_part) {
  __shared__ float x_lds[16][516];
  __shared__ float qt_lds[HH][516];
  __shared__ float c_lds[16][9];
  __shared__ float w_lds[16][9];
  __shared__ float flag_lds[16];
  __shared__ float mml[HH], lsum[HH], alpha_lds[HH];

  const int t = threadIdx.x;
  const int s = blockIdx.x;      // split 0..2
  const int b = blockIdx.y;
  const float* Xb = X + (size_t)b * NN * DD;
  const int t0 = s * 21, t1 = t0 + 21;  // 63 tiles total, 21 each

  for (int i = t; i < HH * 128; i += 256) {
    int r = i >> 7, c4 = i & 127;
    ((float4*)qt_lds[r])[c4] = ((const float4*)(Qt + ((size_t)b * HH + r) * DD))[c4];
  }
  if (t < HH) { mml[t] = -3e38f; lsum[t] = 0.f; }

  const int dsl = t & 15;
  const int n2  = t >> 5;
  const int h4  = (t >> 4) & 1;
  const int cr0 = n2 * 2, cr1 = cr0 + 1;
  const int hb = h4 * 4;
  const int chb = (t >> 7) * 4;
  const int dq  = t & 127;

  float4 ctxv0 = {0,0,0,0}, ctxv1 = {0,0,0,0}, ctxv2 = {0,0,0,0}, ctxv3 = {0,0,0,0};
  float4 pf[8];
  float mfl = 0.f;

  // prefetch first tile
  {
    const int n0 = t0 * 16;
    #pragma unroll
    for (int k = 0; k < 8; ++k) {
      int fl = t + 256 * k;
      int r = fl >> 7, c4 = fl & 127;
      int n = n0 + r;
      pf[k] = (n < NN) ? ((const float4*)(Xb + (size_t)n * DD))[c4]
                       : make_float4(0.f, 0.f, 0.f, 0.f);
    }
    if (t < 16) {
      int n = n0 + t;
      mfl = (n < NN && mask[(size_t)b * NN + n] == 0) ? 1.f : 0.f;
    }
  }
  __syncthreads();

  // register-cache Qt for heads hb, hb+1 (loop-invariant; LDS caps occupancy
  // at 3 blocks/CU anyway so the extra VGPRs are free)
  float4 qtr[16];
  #pragma unroll
  for (int k = 0; k < 8; ++k) {
    qtr[2 * k]     = ((const float4*)qt_lds[hb + 0])[dsl + 16 * k];
    qtr[2 * k + 1] = ((const float4*)qt_lds[hb + 1])[dsl + 16 * k];
  }

  for (int it = t0; it < t1; ++it) {
    // ---- store prefetched tile
    #pragma unroll
    for (int k = 0; k < 8; ++k) {
      int fl = t + 256 * k;
      int r = fl >> 7, c4 = fl & 127;
      ((float4*)x_lds[r])[c4] = pf[k];
    }
    if (t < 16) flag_lds[t] = mfl;
    __syncthreads();  // (A)

    // ---- prefetch next tile
    {
      const int n0 = (it + 1) * 16;
      #pragma unroll
      for (int k = 0; k < 8; ++k) {
        int fl = t + 256 * k;
        int r = fl >> 7, c4 = fl & 127;
        int n = n0 + r;
        pf[k] = (it + 1 < t1 && n < NN)
                    ? ((const float4*)(Xb + (size_t)n * DD))[c4]
                    : make_float4(0.f, 0.f, 0.f, 0.f);
      }
      if (t < 16) {
        int n = n0 + t;
        mfl = (it + 1 < t1 && n < NN && mask[(size_t)b * NN + n] == 0) ? 1.f : 0.f;
      }
    }

    // ---- compat: 2 rows x 4 heads per thread over d-slices dsl+16k
    {
      float a00=0.f,a01=0.f,a02=0.f,a03=0.f;
      float a10=0.f,a11=0.f,a12=0.f,a13=0.f;
      #pragma unroll
      for (int k = 0; k < 8; ++k) {
        const int q = dsl + 16 * k;
        const float4 x0 = ((const float4*)x_lds[cr0])[q];
        const float4 x1 = ((const float4*)x_lds[cr1])[q];
        const float4 q0 = qtr[2 * k];
        const float4 q1 = qtr[2 * k + 1];
        const float4 q2 = ((const float4*)qt_lds[hb + 2])[q];
        const float4 q3 = ((const float4*)qt_lds[hb + 3])[q];
        a00 += x0.x*q0.x + x0.y*q0.y + x0.z*q0.z + x0.w*q0.w;
        a01 += x0.x*q1.x + x0.y*q1.y + x0.z*q1.z + x0.w*q1.w;
        a02 += x0.x*q2.x + x0.y*q2.y + x0.z*q2.z + x0.w*q2.w;
        a03 += x0.x*q3.x + x0.y*q3.y + x0.z*q3.z + x0.w*q3.w;
        a10 += x1.x*q0.x + x1.y*q0.y + x1.z*q0.z + x1.w*q0.w;
        a11 += x1.x*q1.x + x1.y*q1.y + x1.z*q1.z + x1.w*q1.w;
        a12 += x1.x*q2.x + x1.y*q2.y + x1.z*q2.z + x1.w*q2.w;
        a13 += x1.x*q3.x + x1.y*q3.y + x1.z*q3.z + x1.w*q3.w;
      }
      #pragma unroll
      for (int mm = 1; mm < 16; mm <<= 1) {
        a00 += __shfl_xor(a00, mm); a01 += __shfl_xor(a01, mm);
        a02 += __shfl_xor(a02, mm); a03 += __shfl_xor(a03, mm);
        a10 += __shfl_xor(a10, mm); a11 += __shfl_xor(a11, mm);
        a12 += __shfl_xor(a12, mm); a13 += __shfl_xor(a13, mm);
      }
      if (dsl == 0) {
        const bool f0 = flag_lds[cr0] > 0.5f;
        const bool f1 = flag_lds[cr1] > 0.5f;
        c_lds[cr0][hb + 0] = f0 ? a00 : -3e38f;
        c_lds[cr0][hb + 1] = f0 ? a01 : -3e38f;
        c_lds[cr0][hb + 2] = f0 ? a02 : -3e38f;
        c_lds[cr0][hb + 3] = f0 ? a03 : -3e38f;
        c_lds[cr1][hb + 0] = f1 ? a10 : -3e38f;
        c_lds[cr1][hb + 1] = f1 ? a11 : -3e38f;
        c_lds[cr1][hb + 2] = f1 ? a12 : -3e38f;
        c_lds[cr1][hb + 3] = f1 ? a13 : -3e38f;
      }
    }
    __syncthreads();  // (B)

    // ---- fused online-softmax stage (max + exp in one step, within-wave)
    if (t < 128) {
      const int h = t >> 4, n = t & 15;
      float c = c_lds[n][h];
      float tmax = c;
      #pragma unroll
      for (int mm = 1; mm < 16; mm <<= 1) tmax = fmaxf(tmax, __shfl_xor(tmax, mm));
      float m_old = mml[h];
      float new_m = fmaxf(m_old, tmax);
      float alpha = __expf(m_old - new_m);
      float p = (c > -1e37f) ? __expf(c - new_m) : 0.f;
      w_lds[n][h] = p;
      float sum = p;
      #pragma unroll
      for (int mm = 1; mm < 16; mm <<= 1) sum += __shfl_xor(sum, mm);
      if (n == 0) {
        lsum[h] = lsum[h] * alpha + sum;
        mml[h] = new_m;
        alpha_lds[h] = alpha;
      }
    }
    __syncthreads();  // (C)

    // ---- ctx update
    {
      const float al0 = alpha_lds[chb + 0], al1 = alpha_lds[chb + 1];
      const float al2 = alpha_lds[chb + 2], al3 = alpha_lds[chb + 3];
      ctxv0.x *= al0; ctxv0.y *= al0; ctxv0.z *= al0; ctxv0.w *= al0;
      ctxv1.x *= al1; ctxv1.y *= al1; ctxv1.z *= al1; ctxv1.w *= al1;
      ctxv2.x *= al2; ctxv2.y *= al2; ctxv2.z *= al2; ctxv2.w *= al2;
      ctxv3.x *= al3; ctxv3.y *= al3; ctxv3.z *= al3; ctxv3.w *= al3;
      #pragma unroll
      for (int n = 0; n < 16; ++n) {
        const float4 xv = ((const float4*)x_lds[n])[dq];
        const float w0 = w_lds[n][chb + 0];
        const float w1 = w_lds[n][chb + 1];
        const float w2 = w_lds[n][chb + 2];
        const float w3 = w_lds[n][chb + 3];
        ctxv0.x += w0 * xv.x; ctxv0.y += w0 * xv.y; ctxv0.z += w0 * xv.z; ctxv0.w += w0 * xv.w;
        ctxv1.x += w1 * xv.x; ctxv1.y += w1 * xv.y; ctxv1.z += w1 * xv.z; ctxv1.w += w1 * xv.w;
        ctxv2.x += w2 * xv.x; ctxv2.y += w2 * xv.y; ctxv2.z += w2 * xv.z; ctxv2.w += w2 * xv.w;
        ctxv3.x += w3 * xv.x; ctxv3.y += w3 * xv.y; ctxv3.z += w3 * xv.z; ctxv3.w += w3 * xv.w;
      }
    }
    __syncthreads();  // (D) x_lds/w_lds reused next iter
  }

  // ---- write unnormalized partials
  if (t < HH) {
    size_t base = (((size_t)b * 3 + s) * HH + t) * 2;
    ml_part[base + 0] = mml[t];
    ml_part[base + 1] = lsum[t];
  }
  ((float4*)(ctx_part + (((size_t)b * 3 + s) * HH + chb + 0) * DD))[dq] = ctxv0;
  ((float4*)(ctx_part + (((size_t)b * 3 + s) * HH + chb + 1) * DD))[dq] = ctxv1;
  ((float4*)(ctx_part + (((size_t)b * 3 + s) * HH + chb + 2) * DD))[dq] = ctxv2;
  ((float4*)(ctx_part + (((size_t)b * 3 + s) * HH + chb + 3) * DD))[dq] = ctxv3;
}

// ============================================================================
// K4a: merge 3 softmax partials + mha_pre[b,h*64+hd] = ctx[b,h,:] @ Wv[:,h*64+hd]
// ============================================================================
__global__ __launch_bounds__(256) void k_pre_merge(
    const float* __restrict__ ctx_part, const float* __restrict__ ml_part,
    const float* __restrict__ Wv, float* __restrict__ pre) {
  __shared__ float c_lds[8][DD];
  __shared__ float wsplit[8][3];
  const int t = threadIdx.x;
  const int b0 = blockIdx.x * 8;
  const int h = blockIdx.y;
  if (t < 8) {
    const int b = b0 + t;
    float m0 = ml_part[(((size_t)b * 3 + 0) * HH + h) * 2 + 0];
    float l0 = ml_part[(((size_t)b * 3 + 0) * HH + h) * 2 + 1];
    float m1 = ml_part[(((size_t)b * 3 + 1) * HH + h) * 2 + 0];
    float l1 = ml_part[(((size_t)b * 3 + 1) * HH + h) * 2 + 1];
    float m2 = ml_part[(((size_t)b * 3 + 2) * HH + h) * 2 + 0];
    float l2 = ml_part[(((size_t)b * 3 + 2) * HH + h) * 2 + 1];
    float M = fmaxf(m0, fmaxf(m1, m2));
    float e0 = __expf(m0 - M), e1 = __expf(m1 - M), e2 = __expf(m2 - M);
    float inv = 1.0f / (l0 * e0 + l1 * e1 + l2 * e2);
    wsplit[t][0] = e0 * inv; wsplit[t][1] = e1 * inv; wsplit[t][2] = e2 * inv;
  }
  __syncthreads();
  for (int i = t; i < 8 * 128; i += 256) {
    int r = i >> 7, q = i & 127;
    const int b = b0 + r;
    float4 p0 = ((const float4*)(ctx_part + (((size_t)b * 3 + 0) * HH + h) * DD))[q];
    float4 p1 = ((const float4*)(ctx_part + (((size_t)b * 3 + 1) * HH + h) * DD))[q];
    float4 p2 = ((const float4*)(ctx_part + (((size_t)b * 3 + 2) * HH + h) * DD))[q];
    float w0 = wsplit[r][0], w1 = wsplit[r][1], w2 = wsplit[r][2];
    float4 c;
    c.x = w0 * p0.x + w1 * p1.x + w2 * p2.x;
    c.y = w0 * p0.y + w1 * p1.y + w2 * p2.y;
    c.z = w0 * p0.z + w1 * p1.z + w2 * p2.z;
    c.w = w0 * p0.w + w1 * p1.w + w2 * p2.w;
    ((float4*)c_lds[r])[q] = c;
  }
  __syncthreads();
  const int hd = t & 63, g = t >> 6;
  const int r0 = g * 2, r1 = r0 + 1;
  float a0 = 0.f, a1 = 0.f;
  for (int d = 0; d < DD; ++d) {
    float w = Wv[(size_t)d * DD + h * 64 + hd];
    a0 = fmaf(c_lds[r0][d], w, a0);
    a1 = fmaf(c_lds[r1][d], w, a1);
  }
  pre[(size_t)(b0 + r0) * DD + h * 64 + hd] = a0;
  pre[(size_t)(b0 + r1) * DD + h * 64 + hd] = a1;
}

// ============================================================================
// K4b: mha_out = mha_pre @ Wo
// ============================================================================
__global__ __launch_bounds__(256) void k_mo(
    const float* __restrict__ pre, const float* __restrict__ Wo,
    float* __restrict__ mo) {
  __shared__ float p_lds[8][DD];
  const int t = threadIdx.x;
  const int b0 = blockIdx.x * 8;
  const int c0 = blockIdx.y * 64;
  for (int i = t; i < 8 * 128; i += 256) {
    int r = i >> 7, c4 = i & 127;
    ((float4*)p_lds[r])[c4] = ((const float4*)(pre + (size_t)(b0 + r) * DD))[c4];
  }
  __syncthreads();
  const int c = c0 + (t & 63);
  const int g = t >> 6;
  const int r0 = g * 2, r1 = r0 + 1;
  float a0 = 0.f, a1 = 0.f;
  for (int e = 0; e < DD; ++e) {
    float w = Wo[(size_t)e * DD + c];
    a0 = fmaf(p_lds[r0][e], w, a0);
    a1 = fmaf(p_lds[r1][e], w, a1);
  }
  mo[(size_t)(b0 + r0) * DD + c] = a0;
  mo[(size_t)(b0 + r1) * DD + c] = a1;
}

// ============================================================================
// K5a: P[b,d] = (1/sqrt(512)) * Wkp[d,:] . mo[b,:]   (Wkp L2-resident)
// ============================================================================
__global__ __launch_bounds__(256) void k_ptr(
    const float* __restrict__ mo, const float* __restrict__ Wkp,
    float* __restrict__ P) {
  __shared__ float m_lds[DD];
  const int t = threadIdx.x;
  const int b = blockIdx.x;
  ((float2*)m_lds)[t] = ((const float2*)(mo + (size_t)b * DD))[t];
  __syncthreads();
  const float norm = 0.04419417382415922f;  // 1/sqrt(512)
  const float* w0 = Wkp + (size_t)t * DD;
  float a0 = 0.f;
  for (int e = 0; e < DD; e += 4) {
    float4 wa = *(const float4*)(w0 + e);
    a0 += wa.x * m_lds[e] + wa.y * m_lds[e+1] + wa.z * m_lds[e+2] + wa.w * m_lds[e+3];
  }
  P[(size_t)b * DD + t] = norm * a0;
  const float* w1 = Wkp + (size_t)(t + 256) * DD;
  float a1 = 0.f;
  for (int e = 0; e < DD; e += 4) {
    float4 wb = *(const float4*)(w1 + e);
    a1 += wb.x * m_lds[e] + wb.y * m_lds[e+1] + wb.z * m_lds[e+2] + wb.w * m_lds[e+3];
  }
  P[(size_t)b * DD + t + 256] = norm * a1;
}

// ============================================================================
// K5b: logits[b,n] = mask ? -BIG : 10*tanh(X[b,n,:] . P[b,:])
// grid (4, B) -> 4 blocks/CU exactly.
// ============================================================================
__global__ __launch_bounds__(256, 4) void k_logits(
    const float* __restrict__ X, const int* __restrict__ mask,
    const float* __restrict__ P, float* __restrict__ logits) {
  __shared__ float x_lds[16][516];
  __shared__ float p_lds[DD];
  const int t = threadIdx.x;
  const int s = blockIdx.x;      // split 0..3
  const int b = blockIdx.y;
  const float* Xb = X + (size_t)b * NN * DD;
  const int t0 = s * 16, t1 = (s == 3) ? 63 : (t0 + 16);

  ((float2*)p_lds)[t] = ((const float2*)(P + (size_t)b * DD))[t];

  const int n = t >> 4, dsl = t & 15;
  float4 pf[8];
  {
    const int n0 = t0 * 16;
    #pragma unroll
    for (int k = 0; k < 8; ++k) {
      int fl = t + 256 * k;
      int r = fl >> 7, c4 = fl & 127;
      int nn = n0 + r;
      pf[k] = (nn < NN) ? ((const float4*)(Xb + (size_t)nn * DD))[c4]
                        : make_float4(0.f, 0.f, 0.f, 0.f);
    }
  }
  __syncthreads();
  float4 preg[8];
  #pragma unroll
  for (int k = 0; k < 8; ++k) preg[k] = ((const float4*)p_lds)[dsl + 16 * k];

  for (int it = t0; it < t1; ++it) {
    #pragma unroll
    for (int k = 0; k < 8; ++k) {
      int fl = t + 256 * k;
      int r = fl >> 7, c4 = fl & 127;
      ((float4*)x_lds[r])[c4] = pf[k];
    }
    __syncthreads();
    {
      const int n0 = (it + 1) * 16;
      #pragma unroll
      for (int k = 0; k < 8; ++k) {
        int fl = t + 256 * k;
        int r = fl >> 7, c4 = fl & 127;
        int nn = n0 + r;
        pf[k] = (it + 1 < t1 && nn < NN)
                    ? ((const float4*)(Xb + (size_t)nn * DD))[c4]
                    : make_float4(0.f, 0.f, 0.f, 0.f);
      }
    }
    float y = 0.f;
    #pragma unroll
    for (int k = 0; k < 8; ++k) {
      const float4 xv = ((const float4*)x_lds[n])[dsl + 16 * k];
      y += xv.x * preg[k].x + xv.y * preg[k].y + xv.z * preg[k].z + xv.w * preg[k].w;
    }
    #pragma unroll
    for (int mm = 1; mm < 16; mm <<= 1) y += __shfl_xor(y, mm);
    if (dsl == 0) {
      const int nn = it * 16 + n;
      if (nn < NN) {
        bool valid = (mask[(size_t)b * NN + nn] == 0);
        // tanh(y) = 1 - 2/(exp(2y)+1); exp overflow -> inf -> tanh=1 (correct)
        float th = 1.0f - 2.0f / (__expf(2.0f * y) + 1.0f);
        logits[(size_t)b * NN + nn] = valid ? 10.f * th : -3e38f;
      }
    }
    __syncthreads();
  }
}

// ============================================================================
// K5c: scores = softmax over 1000 logits per batch
// ============================================================================
__global__ __launch_bounds__(256) void k_softmax(
    const float* __restrict__ logits, float* __restrict__ out) {
  __shared__ float red[12];
  const int t = threadIdx.x;
  const int b = blockIdx.x;
  const float4* lp = (const float4*)(logits + (size_t)b * NN);
  float4 v = (t < 250) ? lp[t] : make_float4(-3e38f, -3e38f, -3e38f, -3e38f);
  float mx = fmaxf(fmaxf(v.x, v.y), fmaxf(v.z, v.w));
  #pragma unroll
  for (int mm = 1; mm < 64; mm <<= 1) mx = fmaxf(mx, __shfl_xor(mx, mm));
  if ((t & 63) == 0) red[t >> 6] = mx;
  __syncthreads();
  if (t == 0) red[8] = fmaxf(fmaxf(red[0], red[1]), fmaxf(red[2], red[3]));
  __syncthreads();
  const float M = red[8];
  float4 e;
  e.x = (t < 250 && v.x > -1e37f) ? __expf(v.x - M) : 0.f;
  e.y = (t < 250 && v.y > -1e37f) ? __expf(v.y - M) : 0.f;
  e.z = (t < 250 && v.z > -1e37f) ? __expf(v.z - M) : 0.f;
  e.w = (t < 250 && v.w > -1e37f) ? __expf(v.w - M) : 0.f;
  float s = e.x + e.y + e.z + e.w;
  #pragma unroll
  for (int mm = 1; mm < 64; mm <<= 1) s += __shfl_xor(s, mm);
  if ((t & 63) == 0) red[4 + (t >> 6)] = s;
  __syncthreads();
  if (t == 0) red[9] = red[4] + red[5] + red[6] + red[7];
  __syncthreads();
  const float S = red[9];
  const bool uni = (M < -1e37f);  // all masked -> uniform (ref: softmax of zeros)
  const float invS = uni ? 0.f : 1.0f / S;
  if (t < 250) {
    float4 o;
    o.x = uni ? (1.0f / NN) : e.x * invS;
    o.y = uni ? (1.0f / NN) : e.y * invS;
    o.z = uni ? (1.0f / NN) : e.z * invS;
    o.w = uni ? (1.0f / NN) : e.w * invS;
    ((float4*)(out + (size_t)b * NN))[t] = o;
  }
}

// ============================================================================
extern "C" void kernel_launch(void* const* d_in, const int* in_sizes, int n_in,
                              void* d_out, int out_size, void* d_ws, size_t ws_size,
                              hipStream_t stream) {
  const float* X    = (const float*)d_in[0];
  const float* pool = (const float*)d_in[1];
  const float* cap  = (const float*)d_in[2];
  const int*   mask = (const int*)d_in[3];
  const float* Wfc  = (const float*)d_in[4];
  const float* Wfc1 = (const float*)d_in[5];
  const float* Wq   = (const float*)d_in[6];
  const float* Wk   = (const float*)d_in[7];
  const float* Wv   = (const float*)d_in[8];
  const float* Wo   = (const float*)d_in[9];
  const float* Wkp  = (const float*)d_in[10];
  float* out = (float*)d_out;

  float* ws = (float*)d_ws;
  float* state    = ws;                         // 131072
  float* Qt       = state + BB * DD;            // 1048576
  float* ctx_part = Qt + BB * HH * DD;          // 3145728
  float* ml_part  = ctx_part + BB * 3 * HH * DD;// 12288
  float* pre      = ml_part + BB * 3 * HH * 2;  // 131072
  float* mo       = pre + BB * DD;              // 131072
  float* P        = mo + BB * DD;               // 131072
  float* logits   = P + BB * DD;                // 256000   (~19.4 MB total)

  k_state<<<dim3(32, 8), 256, 0, stream>>>(X, pool, cap, Wfc, Wfc1, state);
  k_qt<<<dim3(32, 8), 256, 0, stream>>>(state, Wq, Wk, Qt);
  k_attn<<<dim3(3, BB), 256, 0, stream>>>(X, mask, Qt, ctx_part, ml_part);
  k_pre_merge<<<dim3(32, 8), 256, 0, stream>>>(ctx_part, ml_part, Wv, pre);
  k_mo<<<dim3(32, 8), 256, 0, stream>>>(pre, Wo, mo);
  k_ptr<<<dim3(BB), 256, 0, stream>>>(mo, Wkp, P);
  k_logits<<<dim3(4, BB), 256, 0, stream>>>(X, mask, P, logits);
  k_softmax<<<dim3(BB), 256, 0, stream>>>(logits, out);
}

// Round 3
// 1243.397 us; speedup vs baseline: 1.1284x; 1.1284x over previous
//
#include <hip/hip_runtime.h>
#include <cstdint>
#include <cstddef>

#define BB 256
#define NN 1000
#define DD 512
#define HH 8

// ============================================================================
// K1: state[b,e] = dec_in[b,:] @ W_fc + pool[b,:] @ W_fc1
// ============================================================================
__global__ __launch_bounds__(256) void k_state(
    const float* __restrict__ X, const float* __restrict__ pool,
    const float* __restrict__ cap, const float* __restrict__ Wfc,
    const float* __restrict__ Wfc1, float* __restrict__ state) {
  __shared__ float dec_lds[8][DD];
  __shared__ float pool_lds[8][DD];
  __shared__ float cap_lds[8];
  const int t = threadIdx.x;
  const int b0 = blockIdx.x * 8;
  for (int i = t; i < 8 * 128; i += 256) {
    int r = i >> 7, c4 = i & 127;
    ((float4*)dec_lds[r])[c4]  = ((const float4*)(X + (size_t)(b0 + r) * NN * DD))[c4];
    ((float4*)pool_lds[r])[c4] = ((const float4*)(pool + (size_t)(b0 + r) * DD))[c4];
  }
  if (t < 8) cap_lds[t] = cap[b0 + t];
  __syncthreads();
  const int e = blockIdx.y * 64 + (t & 63);
  const int g = t >> 6;
  const int r0 = g * 2, r1 = r0 + 1;
  float a0 = 0.f, a1 = 0.f;
  for (int d = 0; d < DD; ++d) {
    float w1 = Wfc[(size_t)d * DD + e];
    float w2 = Wfc1[(size_t)d * DD + e];
    a0 = fmaf(dec_lds[r0][d], w1, a0); a0 = fmaf(pool_lds[r0][d], w2, a0);
    a1 = fmaf(dec_lds[r1][d], w1, a1); a1 = fmaf(pool_lds[r1][d], w2, a1);
  }
  float wc = Wfc[(size_t)DD * DD + e];
  a0 += cap_lds[r0] * wc;
  a1 += cap_lds[r1] * wc;
  state[(size_t)(b0 + r0) * DD + e] = a0;
  state[(size_t)(b0 + r1) * DD + e] = a1;
}

// ============================================================================
// K2: Qt[b,h,d] = (1/8) * sum_hd (state[b,:]@Wq)[h*64+hd] * Wk[d, h*64+hd]
// ============================================================================
__global__ __launch_bounds__(256) void k_qt(
    const float* __restrict__ state, const float* __restrict__ Wq,
    const float* __restrict__ Wk, float* __restrict__ Qt) {
  __shared__ float s_lds[8][DD];
  __shared__ float q_lds[8][64];
  __shared__ float wk_lds[64][65];
  const int t = threadIdx.x;
  const int b0 = blockIdx.x * 8;
  const int h = blockIdx.y;
  for (int i = t; i < 8 * 128; i += 256) {
    int r = i >> 7, c4 = i & 127;
    ((float4*)s_lds[r])[c4] = ((const float4*)(state + (size_t)(b0 + r) * DD))[c4];
  }
  __syncthreads();
  const int hd = t & 63;
  const int g = t >> 6;
  const int r0 = g * 2, r1 = r0 + 1;
  {
    float a0 = 0.f, a1 = 0.f;
    for (int e = 0; e < DD; ++e) {
      float w = Wq[(size_t)e * DD + h * 64 + hd];
      a0 = fmaf(s_lds[r0][e], w, a0);
      a1 = fmaf(s_lds[r1][e], w, a1);
    }
    q_lds[r0][hd] = a0;
    q_lds[r1][hd] = a1;
  }
  const float norm = 0.125f;  // 1/sqrt(64)
  for (int dc = 0; dc < DD; dc += 64) {
    __syncthreads();
    for (int i = t; i < 64 * 16; i += 256) {
      int row = i >> 4, c4 = i & 15;
      float4 wv = ((const float4*)(Wk + (size_t)(dc + row) * DD + h * 64))[c4];
      wk_lds[row][c4 * 4 + 0] = wv.x; wk_lds[row][c4 * 4 + 1] = wv.y;
      wk_lds[row][c4 * 4 + 2] = wv.z; wk_lds[row][c4 * 4 + 3] = wv.w;
    }
    __syncthreads();
    const int dl = t & 63;
    float a0 = 0.f, a1 = 0.f;
    for (int k = 0; k < 64; ++k) {
      float w = wk_lds[dl][k];
      a0 = fmaf(q_lds[r0][k], w, a0);
      a1 = fmaf(q_lds[r1][k], w, a1);
    }
    Qt[((size_t)(b0 + r0) * HH + h) * DD + dc + dl] = norm * a0;
    Qt[((size_t)(b0 + r1) * HH + h) * DD + dc + dl] = norm * a1;
  }
}

// ============================================================================
// K3: split-N flash attention. grid (3, B) -> 3 blocks/CU (LDS = 51 KB).
// NOTE (R2 post-mortem): NO register caching of Qt here — qtr[16] float4
// pushed past the VGPR budget and the compiler spilled arrays to scratch
// (FETCH +660 MB, WRITE +306 MB, VALUBusy 10%). All Qt reads stay in LDS.
// ============================================================================
__global__ __launch_bounds__(256, 3) void k_attn(
    const float* __restrict__ X, const int* __restrict__ mask,
    const float* __restrict__ Qt, float* __restrict__ ctx_part,
    float* __restrict__ ml_part) {
  __shared__ float x_lds[16][516];
  __shared__ float qt_lds[HH][516];
  __shared__ float c_lds[16][9];
  __shared__ float w_lds[16][9];
  __shared__ float flag_lds[16];
  __shared__ float mml[HH], lsum[HH], alpha_lds[HH];

  const int t = threadIdx.x;
  const int s = blockIdx.x;      // split 0..2
  const int b = blockIdx.y;
  const float* Xb = X + (size_t)b * NN * DD;
  const int t0 = s * 21, t1 = t0 + 21;  // 63 tiles total, 21 each

  for (int i = t; i < HH * 128; i += 256) {
    int r = i >> 7, c4 = i & 127;
    ((float4*)qt_lds[r])[c4] = ((const float4*)(Qt + ((size_t)b * HH + r) * DD))[c4];
  }
  if (t < HH) { mml[t] = -3e38f; lsum[t] = 0.f; }

  const int dsl = t & 15;
  const int n2  = t >> 5;
  const int h4  = (t >> 4) & 1;
  const int cr0 = n2 * 2, cr1 = cr0 + 1;
  const int hb = h4 * 4;
  const int chb = (t >> 7) * 4;
  const int dq  = t & 127;

  float4 ctxv0 = {0,0,0,0}, ctxv1 = {0,0,0,0}, ctxv2 = {0,0,0,0}, ctxv3 = {0,0,0,0};
  float4 pf[8];
  float mfl = 0.f;

  // prefetch first tile
  {
    const int n0 = t0 * 16;
    #pragma unroll
    for (int k = 0; k < 8; ++k) {
      int fl = t + 256 * k;
      int r = fl >> 7, c4 = fl & 127;
      int n = n0 + r;
      pf[k] = (n < NN) ? ((const float4*)(Xb + (size_t)n * DD))[c4]
                       : make_float4(0.f, 0.f, 0.f, 0.f);
    }
    if (t < 16) {
      int n = n0 + t;
      mfl = (n < NN && mask[(size_t)b * NN + n] == 0) ? 1.f : 0.f;
    }
  }
  __syncthreads();

  for (int it = t0; it < t1; ++it) {
    // ---- store prefetched tile
    #pragma unroll
    for (int k = 0; k < 8; ++k) {
      int fl = t + 256 * k;
      int r = fl >> 7, c4 = fl & 127;
      ((float4*)x_lds[r])[c4] = pf[k];
    }
    if (t < 16) flag_lds[t] = mfl;
    __syncthreads();  // (A)

    // ---- prefetch next tile
    {
      const int n0 = (it + 1) * 16;
      #pragma unroll
      for (int k = 0; k < 8; ++k) {
        int fl = t + 256 * k;
        int r = fl >> 7, c4 = fl & 127;
        int n = n0 + r;
        pf[k] = (it + 1 < t1 && n < NN)
                    ? ((const float4*)(Xb + (size_t)n * DD))[c4]
                    : make_float4(0.f, 0.f, 0.f, 0.f);
      }
      if (t < 16) {
        int n = n0 + t;
        mfl = (it + 1 < t1 && n < NN && mask[(size_t)b * NN + n] == 0) ? 1.f : 0.f;
      }
    }

    // ---- compat: 2 rows x 4 heads per thread over d-slices dsl+16k
    {
      float a00=0.f,a01=0.f,a02=0.f,a03=0.f;
      float a10=0.f,a11=0.f,a12=0.f,a13=0.f;
      #pragma unroll
      for (int k = 0; k < 8; ++k) {
        const int q = dsl + 16 * k;
        const float4 x0 = ((const float4*)x_lds[cr0])[q];
        const float4 x1 = ((const float4*)x_lds[cr1])[q];
        const float4 q0 = ((const float4*)qt_lds[hb + 0])[q];
        const float4 q1 = ((const float4*)qt_lds[hb + 1])[q];
        const float4 q2 = ((const float4*)qt_lds[hb + 2])[q];
        const float4 q3 = ((const float4*)qt_lds[hb + 3])[q];
        a00 += x0.x*q0.x + x0.y*q0.y + x0.z*q0.z + x0.w*q0.w;
        a01 += x0.x*q1.x + x0.y*q1.y + x0.z*q1.z + x0.w*q1.w;
        a02 += x0.x*q2.x + x0.y*q2.y + x0.z*q2.z + x0.w*q2.w;
        a03 += x0.x*q3.x + x0.y*q3.y + x0.z*q3.z + x0.w*q3.w;
        a10 += x1.x*q0.x + x1.y*q0.y + x1.z*q0.z + x1.w*q0.w;
        a11 += x1.x*q1.x + x1.y*q1.y + x1.z*q1.z + x1.w*q1.w;
        a12 += x1.x*q2.x + x1.y*q2.y + x1.z*q2.z + x1.w*q2.w;
        a13 += x1.x*q3.x + x1.y*q3.y + x1.z*q3.z + x1.w*q3.w;
      }
      #pragma unroll
      for (int mm = 1; mm < 16; mm <<= 1) {
        a00 += __shfl_xor(a00, mm); a01 += __shfl_xor(a01, mm);
        a02 += __shfl_xor(a02, mm); a03 += __shfl_xor(a03, mm);
        a10 += __shfl_xor(a10, mm); a11 += __shfl_xor(a11, mm);
        a12 += __shfl_xor(a12, mm); a13 += __shfl_xor(a13, mm);
      }
      if (dsl == 0) {
        const bool f0 = flag_lds[cr0] > 0.5f;
        const bool f1 = flag_lds[cr1] > 0.5f;
        c_lds[cr0][hb + 0] = f0 ? a00 : -3e38f;
        c_lds[cr0][hb + 1] = f0 ? a01 : -3e38f;
        c_lds[cr0][hb + 2] = f0 ? a02 : -3e38f;
        c_lds[cr0][hb + 3] = f0 ? a03 : -3e38f;
        c_lds[cr1][hb + 0] = f1 ? a10 : -3e38f;
        c_lds[cr1][hb + 1] = f1 ? a11 : -3e38f;
        c_lds[cr1][hb + 2] = f1 ? a12 : -3e38f;
        c_lds[cr1][hb + 3] = f1 ? a13 : -3e38f;
      }
    }
    __syncthreads();  // (B)

    // ---- fused online-softmax stage (max + exp in one step, within-wave)
    if (t < 128) {
      const int h = t >> 4, n = t & 15;
      float c = c_lds[n][h];
      float tmax = c;
      #pragma unroll
      for (int mm = 1; mm < 16; mm <<= 1) tmax = fmaxf(tmax, __shfl_xor(tmax, mm));
      float m_old = mml[h];
      float new_m = fmaxf(m_old, tmax);
      float alpha = __expf(m_old - new_m);
      float p = (c > -1e37f) ? __expf(c - new_m) : 0.f;
      w_lds[n][h] = p;
      float sum = p;
      #pragma unroll
      for (int mm = 1; mm < 16; mm <<= 1) sum += __shfl_xor(sum, mm);
      if (n == 0) {
        lsum[h] = lsum[h] * alpha + sum;
        mml[h] = new_m;
        alpha_lds[h] = alpha;
      }
    }
    __syncthreads();  // (C)

    // ---- ctx update
    {
      const float al0 = alpha_lds[chb + 0], al1 = alpha_lds[chb + 1];
      const float al2 = alpha_lds[chb + 2], al3 = alpha_lds[chb + 3];
      ctxv0.x *= al0; ctxv0.y *= al0; ctxv0.z *= al0; ctxv0.w *= al0;
      ctxv1.x *= al1; ctxv1.y *= al1; ctxv1.z *= al1; ctxv1.w *= al1;
      ctxv2.x *= al2; ctxv2.y *= al2; ctxv2.z *= al2; ctxv2.w *= al2;
      ctxv3.x *= al3; ctxv3.y *= al3; ctxv3.z *= al3; ctxv3.w *= al3;
      #pragma unroll
      for (int n = 0; n < 16; ++n) {
        const float4 xv = ((const float4*)x_lds[n])[dq];
        const float w0 = w_lds[n][chb + 0];
        const float w1 = w_lds[n][chb + 1];
        const float w2 = w_lds[n][chb + 2];
        const float w3 = w_lds[n][chb + 3];
        ctxv0.x += w0 * xv.x; ctxv0.y += w0 * xv.y; ctxv0.z += w0 * xv.z; ctxv0.w += w0 * xv.w;
        ctxv1.x += w1 * xv.x; ctxv1.y += w1 * xv.y; ctxv1.z += w1 * xv.z; ctxv1.w += w1 * xv.w;
        ctxv2.x += w2 * xv.x; ctxv2.y += w2 * xv.y; ctxv2.z += w2 * xv.z; ctxv2.w += w2 * xv.w;
        ctxv3.x += w3 * xv.x; ctxv3.y += w3 * xv.y; ctxv3.z += w3 * xv.z; ctxv3.w += w3 * xv.w;
      }
    }
    __syncthreads();  // (D) x_lds/w_lds reused next iter
  }

  // ---- write unnormalized partials
  if (t < HH) {
    size_t base = (((size_t)b * 3 + s) * HH + t) * 2;
    ml_part[base + 0] = mml[t];
    ml_part[base + 1] = lsum[t];
  }
  ((float4*)(ctx_part + (((size_t)b * 3 + s) * HH + chb + 0) * DD))[dq] = ctxv0;
  ((float4*)(ctx_part + (((size_t)b * 3 + s) * HH + chb + 1) * DD))[dq] = ctxv1;
  ((float4*)(ctx_part + (((size_t)b * 3 + s) * HH + chb + 2) * DD))[dq] = ctxv2;
  ((float4*)(ctx_part + (((size_t)b * 3 + s) * HH + chb + 3) * DD))[dq] = ctxv3;
}

// ============================================================================
// K4a: merge 3 softmax partials + mha_pre[b,h*64+hd] = ctx[b,h,:] @ Wv[:,h*64+hd]
// ============================================================================
__global__ __launch_bounds__(256) void k_pre_merge(
    const float* __restrict__ ctx_part, const float* __restrict__ ml_part,
    const float* __restrict__ Wv, float* __restrict__ pre) {
  __shared__ float c_lds[8][DD];
  __shared__ float wsplit[8][3];
  const int t = threadIdx.x;
  const int b0 = blockIdx.x * 8;
  const int h = blockIdx.y;
  if (t < 8) {
    const int b = b0 + t;
    float m0 = ml_part[(((size_t)b * 3 + 0) * HH + h) * 2 + 0];
    float l0 = ml_part[(((size_t)b * 3 + 0) * HH + h) * 2 + 1];
    float m1 = ml_part[(((size_t)b * 3 + 1) * HH + h) * 2 + 0];
    float l1 = ml_part[(((size_t)b * 3 + 1) * HH + h) * 2 + 1];
    float m2 = ml_part[(((size_t)b * 3 + 2) * HH + h) * 2 + 0];
    float l2 = ml_part[(((size_t)b * 3 + 2) * HH + h) * 2 + 1];
    float M = fmaxf(m0, fmaxf(m1, m2));
    float e0 = __expf(m0 - M), e1 = __expf(m1 - M), e2 = __expf(m2 - M);
    float inv = 1.0f / (l0 * e0 + l1 * e1 + l2 * e2);
    wsplit[t][0] = e0 * inv; wsplit[t][1] = e1 * inv; wsplit[t][2] = e2 * inv;
  }
  __syncthreads();
  for (int i = t; i < 8 * 128; i += 256) {
    int r = i >> 7, q = i & 127;
    const int b = b0 + r;
    float4 p0 = ((const float4*)(ctx_part + (((size_t)b * 3 + 0) * HH + h) * DD))[q];
    float4 p1 = ((const float4*)(ctx_part + (((size_t)b * 3 + 1) * HH + h) * DD))[q];
    float4 p2 = ((const float4*)(ctx_part + (((size_t)b * 3 + 2) * HH + h) * DD))[q];
    float w0 = wsplit[r][0], w1 = wsplit[r][1], w2 = wsplit[r][2];
    float4 c;
    c.x = w0 * p0.x + w1 * p1.x + w2 * p2.x;
    c.y = w0 * p0.y + w1 * p1.y + w2 * p2.y;
    c.z = w0 * p0.z + w1 * p1.z + w2 * p2.z;
    c.w = w0 * p0.w + w1 * p1.w + w2 * p2.w;
    ((float4*)c_lds[r])[q] = c;
  }
  __syncthreads();
  const int hd = t & 63, g = t >> 6;
  const int r0 = g * 2, r1 = r0 + 1;
  float a0 = 0.f, a1 = 0.f;
  for (int d = 0; d < DD; ++d) {
    float w = Wv[(size_t)d * DD + h * 64 + hd];
    a0 = fmaf(c_lds[r0][d], w, a0);
    a1 = fmaf(c_lds[r1][d], w, a1);
  }
  pre[(size_t)(b0 + r0) * DD + h * 64 + hd] = a0;
  pre[(size_t)(b0 + r1) * DD + h * 64 + hd] = a1;
}

// ============================================================================
// K4b: mha_out = mha_pre @ Wo
// ============================================================================
__global__ __launch_bounds__(256) void k_mo(
    const float* __restrict__ pre, const float* __restrict__ Wo,
    float* __restrict__ mo) {
  __shared__ float p_lds[8][DD];
  const int t = threadIdx.x;
  const int b0 = blockIdx.x * 8;
  const int c0 = blockIdx.y * 64;
  for (int i = t; i < 8 * 128; i += 256) {
    int r = i >> 7, c4 = i & 127;
    ((float4*)p_lds[r])[c4] = ((const float4*)(pre + (size_t)(b0 + r) * DD))[c4];
  }
  __syncthreads();
  const int c = c0 + (t & 63);
  const int g = t >> 6;
  const int r0 = g * 2, r1 = r0 + 1;
  float a0 = 0.f, a1 = 0.f;
  for (int e = 0; e < DD; ++e) {
    float w = Wo[(size_t)e * DD + c];
    a0 = fmaf(p_lds[r0][e], w, a0);
    a1 = fmaf(p_lds[r1][e], w, a1);
  }
  mo[(size_t)(b0 + r0) * DD + c] = a0;
  mo[(size_t)(b0 + r1) * DD + c] = a1;
}

// ============================================================================
// K5a: P[b,d] = (1/sqrt(512)) * Wkp[d,:] . mo[b,:]   (Wkp L2-resident)
// ============================================================================
__global__ __launch_bounds__(256) void k_ptr(
    const float* __restrict__ mo, const float* __restrict__ Wkp,
    float* __restrict__ P) {
  __shared__ float m_lds[DD];
  const int t = threadIdx.x;
  const int b = blockIdx.x;
  ((float2*)m_lds)[t] = ((const float2*)(mo + (size_t)b * DD))[t];
  __syncthreads();
  const float norm = 0.04419417382415922f;  // 1/sqrt(512)
  const float* w0 = Wkp + (size_t)t * DD;
  float a0 = 0.f;
  for (int e = 0; e < DD; e += 4) {
    float4 wa = *(const float4*)(w0 + e);
    a0 += wa.x * m_lds[e] + wa.y * m_lds[e+1] + wa.z * m_lds[e+2] + wa.w * m_lds[e+3];
  }
  P[(size_t)b * DD + t] = norm * a0;
  const float* w1 = Wkp + (size_t)(t + 256) * DD;
  float a1 = 0.f;
  for (int e = 0; e < DD; e += 4) {
    float4 wb = *(const float4*)(w1 + e);
    a1 += wb.x * m_lds[e] + wb.y * m_lds[e+1] + wb.z * m_lds[e+2] + wb.w * m_lds[e+3];
  }
  P[(size_t)b * DD + t + 256] = norm * a1;
}

// ============================================================================
// K5b: logits[b,n] = mask ? -BIG : 10*tanh(X[b,n,:] . P[b,:])
// grid (4, B) -> 4 blocks/CU exactly.
// ============================================================================
__global__ __launch_bounds__(256, 4) void k_logits(
    const float* __restrict__ X, const int* __restrict__ mask,
    const float* __restrict__ P, float* __restrict__ logits) {
  __shared__ float x_lds[16][516];
  __shared__ float p_lds[DD];
  const int t = threadIdx.x;
  const int s = blockIdx.x;      // split 0..3
  const int b = blockIdx.y;
  const float* Xb = X + (size_t)b * NN * DD;
  const int t0 = s * 16, t1 = (s == 3) ? 63 : (t0 + 16);

  ((float2*)p_lds)[t] = ((const float2*)(P + (size_t)b * DD))[t];

  const int n = t >> 4, dsl = t & 15;
  float4 pf[8];
  {
    const int n0 = t0 * 16;
    #pragma unroll
    for (int k = 0; k < 8; ++k) {
      int fl = t + 256 * k;
      int r = fl >> 7, c4 = fl & 127;
      int nn = n0 + r;
      pf[k] = (nn < NN) ? ((const float4*)(Xb + (size_t)nn * DD))[c4]
                        : make_float4(0.f, 0.f, 0.f, 0.f);
    }
  }
  __syncthreads();
  float4 preg[8];
  #pragma unroll
  for (int k = 0; k < 8; ++k) preg[k] = ((const float4*)p_lds)[dsl + 16 * k];

  for (int it = t0; it < t1; ++it) {
    #pragma unroll
    for (int k = 0; k < 8; ++k) {
      int fl = t + 256 * k;
      int r = fl >> 7, c4 = fl & 127;
      ((float4*)x_lds[r])[c4] = pf[k];
    }
    __syncthreads();
    {
      const int n0 = (it + 1) * 16;
      #pragma unroll
      for (int k = 0; k < 8; ++k) {
        int fl = t + 256 * k;
        int r = fl >> 7, c4 = fl & 127;
        int nn = n0 + r;
        pf[k] = (it + 1 < t1 && nn < NN)
                    ? ((const float4*)(Xb + (size_t)nn * DD))[c4]
                    : make_float4(0.f, 0.f, 0.f, 0.f);
      }
    }
    float y = 0.f;
    #pragma unroll
    for (int k = 0; k < 8; ++k) {
      const float4 xv = ((const float4*)x_lds[n])[dsl + 16 * k];
      y += xv.x * preg[k].x + xv.y * preg[k].y + xv.z * preg[k].z + xv.w * preg[k].w;
    }
    #pragma unroll
    for (int mm = 1; mm < 16; mm <<= 1) y += __shfl_xor(y, mm);
    if (dsl == 0) {
      const int nn = it * 16 + n;
      if (nn < NN) {
        bool valid = (mask[(size_t)b * NN + nn] == 0);
        // tanh(y) = 1 - 2/(exp(2y)+1); exp overflow -> inf -> tanh=1 (correct)
        float th = 1.0f - 2.0f / (__expf(2.0f * y) + 1.0f);
        logits[(size_t)b * NN + nn] = valid ? 10.f * th : -3e38f;
      }
    }
    __syncthreads();
  }
}

// ============================================================================
// K5c: scores = softmax over 1000 logits per batch
// ============================================================================
__global__ __launch_bounds__(256) void k_softmax(
    const float* __restrict__ logits, float* __restrict__ out) {
  __shared__ float red[12];
  const int t = threadIdx.x;
  const int b = blockIdx.x;
  const float4* lp = (const float4*)(logits + (size_t)b * NN);
  float4 v = (t < 250) ? lp[t] : make_float4(-3e38f, -3e38f, -3e38f, -3e38f);
  float mx = fmaxf(fmaxf(v.x, v.y), fmaxf(v.z, v.w));
  #pragma unroll
  for (int mm = 1; mm < 64; mm <<= 1) mx = fmaxf(mx, __shfl_xor(mx, mm));
  if ((t & 63) == 0) red[t >> 6] = mx;
  __syncthreads();
  if (t == 0) red[8] = fmaxf(fmaxf(red[0], red[1]), fmaxf(red[2], red[3]));
  __syncthreads();
  const float M = red[8];
  float4 e;
  e.x = (t < 250 && v.x > -1e37f) ? __expf(v.x - M) : 0.f;
  e.y = (t < 250 && v.y > -1e37f) ? __expf(v.y - M) : 0.f;
  e.z = (t < 250 && v.z > -1e37f) ? __expf(v.z - M) : 0.f;
  e.w = (t < 250 && v.w > -1e37f) ? __expf(v.w - M) : 0.f;
  float s = e.x + e.y + e.z + e.w;
  #pragma unroll
  for (int mm = 1; mm < 64; mm <<= 1) s += __shfl_xor(s, mm);
  if ((t & 63) == 0) red[4 + (t >> 6)] = s;
  __syncthreads();
  if (t == 0) red[9] = red[4] + red[5] + red[6] + red[7];
  __syncthreads();
  const float S = red[9];
  const bool uni = (M < -1e37f);  // all masked -> uniform (ref: softmax of zeros)
  const float invS = uni ? 0.f : 1.0f / S;
  if (t < 250) {
    float4 o;
    o.x = uni ? (1.0f / NN) : e.x * invS;
    o.y = uni ? (1.0f / NN) : e.y * invS;
    o.z = uni ? (1.0f / NN) : e.z * invS;
    o.w = uni ? (1.0f / NN) : e.w * invS;
    ((float4*)(out + (size_t)b * NN))[t] = o;
  }
}

// ============================================================================
extern "C" void kernel_launch(void* const* d_in, const int* in_sizes, int n_in,
                              void* d_out, int out_size, void* d_ws, size_t ws_size,
                              hipStream_t stream) {
  const float* X    = (const float*)d_in[0];
  const float* pool = (const float*)d_in[1];
  const float* cap  = (const float*)d_in[2];
  const int*   mask = (const int*)d_in[3];
  const float* Wfc  = (const float*)d_in[4];
  const float* Wfc1 = (const float*)d_in[5];
  const float* Wq   = (const float*)d_in[6];
  const float* Wk   = (const float*)d_in[7];
  const float* Wv   = (const float*)d_in[8];
  const float* Wo   = (const float*)d_in[9];
  const float* Wkp  = (const float*)d_in[10];
  float* out = (float*)d_out;

  float* ws = (float*)d_ws;
  float* state    = ws;                         // 131072
  float* Qt       = state + BB * DD;            // 1048576
  float* ctx_part = Qt + BB * HH * DD;          // 3145728
  float* ml_part  = ctx_part + BB * 3 * HH * DD;// 12288
  float* pre      = ml_part + BB * 3 * HH * 2;  // 131072
  float* mo       = pre + BB * DD;              // 131072
  float* P        = mo + BB * DD;               // 131072
  float* logits   = P + BB * DD;                // 256000   (~19.4 MB total)

  k_state<<<dim3(32, 8), 256, 0, stream>>>(X, pool, cap, Wfc, Wfc1, state);
  k_qt<<<dim3(32, 8), 256, 0, stream>>>(state, Wq, Wk, Qt);
  k_attn<<<dim3(3, BB), 256, 0, stream>>>(X, mask, Qt, ctx_part, ml_part);
  k_pre_merge<<<dim3(32, 8), 256, 0, stream>>>(ctx_part, ml_part, Wv, pre);
  k_mo<<<dim3(32, 8), 256, 0, stream>>>(pre, Wo, mo);
  k_ptr<<<dim3(BB), 256, 0, stream>>>(mo, Wkp, P);
  k_logits<<<dim3(4, BB), 256, 0, stream>>>(X, mask, P, logits);
  k_softmax<<<dim3(BB), 256, 0, stream>>>(logits, out);
}

// Round 4
// 1057.765 us; speedup vs baseline: 1.3265x; 1.1755x over previous
//
#include <hip/hip_runtime.h>
#include <cstdint>
#include <cstddef>

#define BB 256
#define NN 1000
#define DD 512
#define HH 8

// ============================================================================
// K1: state[b,e] = dec_in[b,:] @ W_fc + pool[b,:] @ W_fc1
// ============================================================================
__global__ __launch_bounds__(256) void k_state(
    const float* __restrict__ X, const float* __restrict__ pool,
    const float* __restrict__ cap, const float* __restrict__ Wfc,
    const float* __restrict__ Wfc1, float* __restrict__ state) {
  __shared__ float dec_lds[8][DD];
  __shared__ float pool_lds[8][DD];
  __shared__ float cap_lds[8];
  const int t = threadIdx.x;
  const int b0 = blockIdx.x * 8;
  for (int i = t; i < 8 * 128; i += 256) {
    int r = i >> 7, c4 = i & 127;
    ((float4*)dec_lds[r])[c4]  = ((const float4*)(X + (size_t)(b0 + r) * NN * DD))[c4];
    ((float4*)pool_lds[r])[c4] = ((const float4*)(pool + (size_t)(b0 + r) * DD))[c4];
  }
  if (t < 8) cap_lds[t] = cap[b0 + t];
  __syncthreads();
  const int e = blockIdx.y * 64 + (t & 63);
  const int g = t >> 6;
  const int r0 = g * 2, r1 = r0 + 1;
  float a0 = 0.f, a1 = 0.f;
  for (int d = 0; d < DD; ++d) {
    float w1 = Wfc[(size_t)d * DD + e];
    float w2 = Wfc1[(size_t)d * DD + e];
    a0 = fmaf(dec_lds[r0][d], w1, a0); a0 = fmaf(pool_lds[r0][d], w2, a0);
    a1 = fmaf(dec_lds[r1][d], w1, a1); a1 = fmaf(pool_lds[r1][d], w2, a1);
  }
  float wc = Wfc[(size_t)DD * DD + e];
  a0 += cap_lds[r0] * wc;
  a1 += cap_lds[r1] * wc;
  state[(size_t)(b0 + r0) * DD + e] = a0;
  state[(size_t)(b0 + r1) * DD + e] = a1;
}

// ============================================================================
// K2: Qt[b,h,d] = (1/8) * sum_hd (state[b,:]@Wq)[h*64+hd] * Wk[d, h*64+hd]
// ============================================================================
__global__ __launch_bounds__(256) void k_qt(
    const float* __restrict__ state, const float* __restrict__ Wq,
    const float* __restrict__ Wk, float* __restrict__ Qt) {
  __shared__ float s_lds[8][DD];
  __shared__ float q_lds[8][64];
  __shared__ float wk_lds[64][65];
  const int t = threadIdx.x;
  const int b0 = blockIdx.x * 8;
  const int h = blockIdx.y;
  for (int i = t; i < 8 * 128; i += 256) {
    int r = i >> 7, c4 = i & 127;
    ((float4*)s_lds[r])[c4] = ((const float4*)(state + (size_t)(b0 + r) * DD))[c4];
  }
  __syncthreads();
  const int hd = t & 63;
  const int g = t >> 6;
  const int r0 = g * 2, r1 = r0 + 1;
  {
    float a0 = 0.f, a1 = 0.f;
    for (int e = 0; e < DD; ++e) {
      float w = Wq[(size_t)e * DD + h * 64 + hd];
      a0 = fmaf(s_lds[r0][e], w, a0);
      a1 = fmaf(s_lds[r1][e], w, a1);
    }
    q_lds[r0][hd] = a0;
    q_lds[r1][hd] = a1;
  }
  const float norm = 0.125f;  // 1/sqrt(64)
  for (int dc = 0; dc < DD; dc += 64) {
    __syncthreads();
    for (int i = t; i < 64 * 16; i += 256) {
      int row = i >> 4, c4 = i & 15;
      float4 wv = ((const float4*)(Wk + (size_t)(dc + row) * DD + h * 64))[c4];
      wk_lds[row][c4 * 4 + 0] = wv.x; wk_lds[row][c4 * 4 + 1] = wv.y;
      wk_lds[row][c4 * 4 + 2] = wv.z; wk_lds[row][c4 * 4 + 3] = wv.w;
    }
    __syncthreads();
    const int dl = t & 63;
    float a0 = 0.f, a1 = 0.f;
    for (int k = 0; k < 64; ++k) {
      float w = wk_lds[dl][k];
      a0 = fmaf(q_lds[r0][k], w, a0);
      a1 = fmaf(q_lds[r1][k], w, a1);
    }
    Qt[((size_t)(b0 + r0) * HH + h) * DD + dc + dl] = norm * a0;
    Qt[((size_t)(b0 + r1) * HH + h) * DD + dc + dl] = norm * a1;
  }
}

// ============================================================================
// K3: split-N flash attention. grid (3, B); LDS 51.2 KB -> 3 blocks/CU.
// R3 post-mortem: __launch_bounds__(256,3) made the allocator pin VGPRs at 84
// while demand is ~110 (pf[8]=32 + ctxv=16 + accums + addressing), causing
// per-iteration scratch spills (WRITE_SIZE 197 MB vs 13 MB ideal). (256,2)
// raises the cap to 256; 3 waves/SIMD only needs <=170 regs, so occupancy
// is unchanged (LDS-bound at 3 blocks/CU) and spills should vanish.
// ============================================================================
__global__ __launch_bounds__(256, 2) void k_attn(
    const float* __restrict__ X, const int* __restrict__ mask,
    const float* __restrict__ Qt, float* __restrict__ ctx_part,
    float* __restrict__ ml_part) {
  __shared__ float x_lds[16][516];
  __shared__ float qt_lds[HH][516];
  __shared__ float c_lds[16][9];
  __shared__ float w_lds[16][9];
  __shared__ float flag_lds[16];
  __shared__ float mml[HH], lsum[HH], alpha_lds[HH];

  const int t = threadIdx.x;
  const int s = blockIdx.x;      // split 0..2
  const int b = blockIdx.y;
  const float* Xb = X + (size_t)b * NN * DD;
  const int t0 = s * 21, t1 = t0 + 21;  // 63 tiles total, 21 each

  for (int i = t; i < HH * 128; i += 256) {
    int r = i >> 7, c4 = i & 127;
    ((float4*)qt_lds[r])[c4] = ((const float4*)(Qt + ((size_t)b * HH + r) * DD))[c4];
  }
  if (t < HH) { mml[t] = -3e38f; lsum[t] = 0.f; }

  const int dsl = t & 15;
  const int n2  = t >> 5;
  const int h4  = (t >> 4) & 1;
  const int cr0 = n2 * 2, cr1 = cr0 + 1;
  const int hb = h4 * 4;
  const int chb = (t >> 7) * 4;
  const int dq  = t & 127;

  float4 ctxv0 = {0,0,0,0}, ctxv1 = {0,0,0,0}, ctxv2 = {0,0,0,0}, ctxv3 = {0,0,0,0};
  float4 pf[8];
  float mfl = 0.f;

  // prefetch first tile
  {
    const int n0 = t0 * 16;
    #pragma unroll
    for (int k = 0; k < 8; ++k) {
      int fl = t + 256 * k;
      int r = fl >> 7, c4 = fl & 127;
      int n = n0 + r;
      pf[k] = (n < NN) ? ((const float4*)(Xb + (size_t)n * DD))[c4]
                       : make_float4(0.f, 0.f, 0.f, 0.f);
    }
    if (t < 16) {
      int n = n0 + t;
      mfl = (n < NN && mask[(size_t)b * NN + n] == 0) ? 1.f : 0.f;
    }
  }
  __syncthreads();

  for (int it = t0; it < t1; ++it) {
    // ---- store prefetched tile
    #pragma unroll
    for (int k = 0; k < 8; ++k) {
      int fl = t + 256 * k;
      int r = fl >> 7, c4 = fl & 127;
      ((float4*)x_lds[r])[c4] = pf[k];
    }
    if (t < 16) flag_lds[t] = mfl;
    __syncthreads();  // (A)

    // ---- prefetch next tile
    {
      const int n0 = (it + 1) * 16;
      #pragma unroll
      for (int k = 0; k < 8; ++k) {
        int fl = t + 256 * k;
        int r = fl >> 7, c4 = fl & 127;
        int n = n0 + r;
        pf[k] = (it + 1 < t1 && n < NN)
                    ? ((const float4*)(Xb + (size_t)n * DD))[c4]
                    : make_float4(0.f, 0.f, 0.f, 0.f);
      }
      if (t < 16) {
        int n = n0 + t;
        mfl = (it + 1 < t1 && n < NN && mask[(size_t)b * NN + n] == 0) ? 1.f : 0.f;
      }
    }

    // ---- compat: 2 rows x 4 heads per thread over d-slices dsl+16k
    {
      float a00=0.f,a01=0.f,a02=0.f,a03=0.f;
      float a10=0.f,a11=0.f,a12=0.f,a13=0.f;
      #pragma unroll
      for (int k = 0; k < 8; ++k) {
        const int q = dsl + 16 * k;
        const float4 x0 = ((const float4*)x_lds[cr0])[q];
        const float4 x1 = ((const float4*)x_lds[cr1])[q];
        const float4 q0 = ((const float4*)qt_lds[hb + 0])[q];
        const float4 q1 = ((const float4*)qt_lds[hb + 1])[q];
        const float4 q2 = ((const float4*)qt_lds[hb + 2])[q];
        const float4 q3 = ((const float4*)qt_lds[hb + 3])[q];
        a00 += x0.x*q0.x + x0.y*q0.y + x0.z*q0.z + x0.w*q0.w;
        a01 += x0.x*q1.x + x0.y*q1.y + x0.z*q1.z + x0.w*q1.w;
        a02 += x0.x*q2.x + x0.y*q2.y + x0.z*q2.z + x0.w*q2.w;
        a03 += x0.x*q3.x + x0.y*q3.y + x0.z*q3.z + x0.w*q3.w;
        a10 += x1.x*q0.x + x1.y*q0.y + x1.z*q0.z + x1.w*q0.w;
        a11 += x1.x*q1.x + x1.y*q1.y + x1.z*q1.z + x1.w*q1.w;
        a12 += x1.x*q2.x + x1.y*q2.y + x1.z*q2.z + x1.w*q2.w;
        a13 += x1.x*q3.x + x1.y*q3.y + x1.z*q3.z + x1.w*q3.w;
      }
      #pragma unroll
      for (int mm = 1; mm < 16; mm <<= 1) {
        a00 += __shfl_xor(a00, mm); a01 += __shfl_xor(a01, mm);
        a02 += __shfl_xor(a02, mm); a03 += __shfl_xor(a03, mm);
        a10 += __shfl_xor(a10, mm); a11 += __shfl_xor(a11, mm);
        a12 += __shfl_xor(a12, mm); a13 += __shfl_xor(a13, mm);
      }
      if (dsl == 0) {
        const bool f0 = flag_lds[cr0] > 0.5f;
        const bool f1 = flag_lds[cr1] > 0.5f;
        c_lds[cr0][hb + 0] = f0 ? a00 : -3e38f;
        c_lds[cr0][hb + 1] = f0 ? a01 : -3e38f;
        c_lds[cr0][hb + 2] = f0 ? a02 : -3e38f;
        c_lds[cr0][hb + 3] = f0 ? a03 : -3e38f;
        c_lds[cr1][hb + 0] = f1 ? a10 : -3e38f;
        c_lds[cr1][hb + 1] = f1 ? a11 : -3e38f;
        c_lds[cr1][hb + 2] = f1 ? a12 : -3e38f;
        c_lds[cr1][hb + 3] = f1 ? a13 : -3e38f;
      }
    }
    __syncthreads();  // (B)

    // ---- fused online-softmax stage (max + exp in one step, within-wave)
    if (t < 128) {
      const int h = t >> 4, n = t & 15;
      float c = c_lds[n][h];
      float tmax = c;
      #pragma unroll
      for (int mm = 1; mm < 16; mm <<= 1) tmax = fmaxf(tmax, __shfl_xor(tmax, mm));
      float m_old = mml[h];
      float new_m = fmaxf(m_old, tmax);
      float alpha = __expf(m_old - new_m);
      float p = (c > -1e37f) ? __expf(c - new_m) : 0.f;
      w_lds[n][h] = p;
      float sum = p;
      #pragma unroll
      for (int mm = 1; mm < 16; mm <<= 1) sum += __shfl_xor(sum, mm);
      if (n == 0) {
        lsum[h] = lsum[h] * alpha + sum;
        mml[h] = new_m;
        alpha_lds[h] = alpha;
      }
    }
    __syncthreads();  // (C)

    // ---- ctx update
    {
      const float al0 = alpha_lds[chb + 0], al1 = alpha_lds[chb + 1];
      const float al2 = alpha_lds[chb + 2], al3 = alpha_lds[chb + 3];
      ctxv0.x *= al0; ctxv0.y *= al0; ctxv0.z *= al0; ctxv0.w *= al0;
      ctxv1.x *= al1; ctxv1.y *= al1; ctxv1.z *= al1; ctxv1.w *= al1;
      ctxv2.x *= al2; ctxv2.y *= al2; ctxv2.z *= al2; ctxv2.w *= al2;
      ctxv3.x *= al3; ctxv3.y *= al3; ctxv3.z *= al3; ctxv3.w *= al3;
      #pragma unroll
      for (int n = 0; n < 16; ++n) {
        const float4 xv = ((const float4*)x_lds[n])[dq];
        const float w0 = w_lds[n][chb + 0];
        const float w1 = w_lds[n][chb + 1];
        const float w2 = w_lds[n][chb + 2];
        const float w3 = w_lds[n][chb + 3];
        ctxv0.x += w0 * xv.x; ctxv0.y += w0 * xv.y; ctxv0.z += w0 * xv.z; ctxv0.w += w0 * xv.w;
        ctxv1.x += w1 * xv.x; ctxv1.y += w1 * xv.y; ctxv1.z += w1 * xv.z; ctxv1.w += w1 * xv.w;
        ctxv2.x += w2 * xv.x; ctxv2.y += w2 * xv.y; ctxv2.z += w2 * xv.z; ctxv2.w += w2 * xv.w;
        ctxv3.x += w3 * xv.x; ctxv3.y += w3 * xv.y; ctxv3.z += w3 * xv.z; ctxv3.w += w3 * xv.w;
      }
    }
    __syncthreads();  // (D) x_lds/w_lds reused next iter
  }

  // ---- write unnormalized partials
  if (t < HH) {
    size_t base = (((size_t)b * 3 + s) * HH + t) * 2;
    ml_part[base + 0] = mml[t];
    ml_part[base + 1] = lsum[t];
  }
  ((float4*)(ctx_part + (((size_t)b * 3 + s) * HH + chb + 0) * DD))[dq] = ctxv0;
  ((float4*)(ctx_part + (((size_t)b * 3 + s) * HH + chb + 1) * DD))[dq] = ctxv1;
  ((float4*)(ctx_part + (((size_t)b * 3 + s) * HH + chb + 2) * DD))[dq] = ctxv2;
  ((float4*)(ctx_part + (((size_t)b * 3 + s) * HH + chb + 3) * DD))[dq] = ctxv3;
}

// ============================================================================
// K4a: merge 3 softmax partials + mha_pre[b,h*64+hd] = ctx[b,h,:] @ Wv[:,h*64+hd]
// ============================================================================
__global__ __launch_bounds__(256) void k_pre_merge(
    const float* __restrict__ ctx_part, const float* __restrict__ ml_part,
    const float* __restrict__ Wv, float* __restrict__ pre) {
  __shared__ float c_lds[8][DD];
  __shared__ float wsplit[8][3];
  const int t = threadIdx.x;
  const int b0 = blockIdx.x * 8;
  const int h = blockIdx.y;
  if (t < 8) {
    const int b = b0 + t;
    float m0 = ml_part[(((size_t)b * 3 + 0) * HH + h) * 2 + 0];
    float l0 = ml_part[(((size_t)b * 3 + 0) * HH + h) * 2 + 1];
    float m1 = ml_part[(((size_t)b * 3 + 1) * HH + h) * 2 + 0];
    float l1 = ml_part[(((size_t)b * 3 + 1) * HH + h) * 2 + 1];
    float m2 = ml_part[(((size_t)b * 3 + 2) * HH + h) * 2 + 0];
    float l2 = ml_part[(((size_t)b * 3 + 2) * HH + h) * 2 + 1];
    float M = fmaxf(m0, fmaxf(m1, m2));
    float e0 = __expf(m0 - M), e1 = __expf(m1 - M), e2 = __expf(m2 - M);
    float inv = 1.0f / (l0 * e0 + l1 * e1 + l2 * e2);
    wsplit[t][0] = e0 * inv; wsplit[t][1] = e1 * inv; wsplit[t][2] = e2 * inv;
  }
  __syncthreads();
  for (int i = t; i < 8 * 128; i += 256) {
    int r = i >> 7, q = i & 127;
    const int b = b0 + r;
    float4 p0 = ((const float4*)(ctx_part + (((size_t)b * 3 + 0) * HH + h) * DD))[q];
    float4 p1 = ((const float4*)(ctx_part + (((size_t)b * 3 + 1) * HH + h) * DD))[q];
    float4 p2 = ((const float4*)(ctx_part + (((size_t)b * 3 + 2) * HH + h) * DD))[q];
    float w0 = wsplit[r][0], w1 = wsplit[r][1], w2 = wsplit[r][2];
    float4 c;
    c.x = w0 * p0.x + w1 * p1.x + w2 * p2.x;
    c.y = w0 * p0.y + w1 * p1.y + w2 * p2.y;
    c.z = w0 * p0.z + w1 * p1.z + w2 * p2.z;
    c.w = w0 * p0.w + w1 * p1.w + w2 * p2.w;
    ((float4*)c_lds[r])[q] = c;
  }
  __syncthreads();
  const int hd = t & 63, g = t >> 6;
  const int r0 = g * 2, r1 = r0 + 1;
  float a0 = 0.f, a1 = 0.f;
  for (int d = 0; d < DD; ++d) {
    float w = Wv[(size_t)d * DD + h * 64 + hd];
    a0 = fmaf(c_lds[r0][d], w, a0);
    a1 = fmaf(c_lds[r1][d], w, a1);
  }
  pre[(size_t)(b0 + r0) * DD + h * 64 + hd] = a0;
  pre[(size_t)(b0 + r1) * DD + h * 64 + hd] = a1;
}

// ============================================================================
// K4b: mha_out = mha_pre @ Wo
// ============================================================================
__global__ __launch_bounds__(256) void k_mo(
    const float* __restrict__ pre, const float* __restrict__ Wo,
    float* __restrict__ mo) {
  __shared__ float p_lds[8][DD];
  const int t = threadIdx.x;
  const int b0 = blockIdx.x * 8;
  const int c0 = blockIdx.y * 64;
  for (int i = t; i < 8 * 128; i += 256) {
    int r = i >> 7, c4 = i & 127;
    ((float4*)p_lds[r])[c4] = ((const float4*)(pre + (size_t)(b0 + r) * DD))[c4];
  }
  __syncthreads();
  const int c = c0 + (t & 63);
  const int g = t >> 6;
  const int r0 = g * 2, r1 = r0 + 1;
  float a0 = 0.f, a1 = 0.f;
  for (int e = 0; e < DD; ++e) {
    float w = Wo[(size_t)e * DD + c];
    a0 = fmaf(p_lds[r0][e], w, a0);
    a1 = fmaf(p_lds[r1][e], w, a1);
  }
  mo[(size_t)(b0 + r0) * DD + c] = a0;
  mo[(size_t)(b0 + r1) * DD + c] = a1;
}

// ============================================================================
// K5a: P[b,d] = (1/sqrt(512)) * Wkp[d,:] . mo[b,:]   (Wkp L2-resident)
// ============================================================================
__global__ __launch_bounds__(256) void k_ptr(
    const float* __restrict__ mo, const float* __restrict__ Wkp,
    float* __restrict__ P) {
  __shared__ float m_lds[DD];
  const int t = threadIdx.x;
  const int b = blockIdx.x;
  ((float2*)m_lds)[t] = ((const float2*)(mo + (size_t)b * DD))[t];
  __syncthreads();
  const float norm = 0.04419417382415922f;  // 1/sqrt(512)
  const float* w0 = Wkp + (size_t)t * DD;
  float a0 = 0.f;
  for (int e = 0; e < DD; e += 4) {
    float4 wa = *(const float4*)(w0 + e);
    a0 += wa.x * m_lds[e] + wa.y * m_lds[e+1] + wa.z * m_lds[e+2] + wa.w * m_lds[e+3];
  }
  P[(size_t)b * DD + t] = norm * a0;
  const float* w1 = Wkp + (size_t)(t + 256) * DD;
  float a1 = 0.f;
  for (int e = 0; e < DD; e += 4) {
    float4 wb = *(const float4*)(w1 + e);
    a1 += wb.x * m_lds[e] + wb.y * m_lds[e+1] + wb.z * m_lds[e+2] + wb.w * m_lds[e+3];
  }
  P[(size_t)b * DD + t + 256] = norm * a1;
}

// ============================================================================
// K5b: logits[b,n] = mask ? -BIG : 10*tanh(X[b,n,:] . P[b,:])
// grid (4, B). (256,4) -> (256,2): same spill-risk as k_attn (pf 32 + preg 32
// + misc vs 128-reg cap was borderline).
// ============================================================================
__global__ __launch_bounds__(256, 2) void k_logits(
    const float* __restrict__ X, const int* __restrict__ mask,
    const float* __restrict__ P, float* __restrict__ logits) {
  __shared__ float x_lds[16][516];
  __shared__ float p_lds[DD];
  const int t = threadIdx.x;
  const int s = blockIdx.x;      // split 0..3
  const int b = blockIdx.y;
  const float* Xb = X + (size_t)b * NN * DD;
  const int t0 = s * 16, t1 = (s == 3) ? 63 : (t0 + 16);

  ((float2*)p_lds)[t] = ((const float2*)(P + (size_t)b * DD))[t];

  const int n = t >> 4, dsl = t & 15;
  float4 pf[8];
  {
    const int n0 = t0 * 16;
    #pragma unroll
    for (int k = 0; k < 8; ++k) {
      int fl = t + 256 * k;
      int r = fl >> 7, c4 = fl & 127;
      int nn = n0 + r;
      pf[k] = (nn < NN) ? ((const float4*)(Xb + (size_t)nn * DD))[c4]
                        : make_float4(0.f, 0.f, 0.f, 0.f);
    }
  }
  __syncthreads();
  float4 preg[8];
  #pragma unroll
  for (int k = 0; k < 8; ++k) preg[k] = ((const float4*)p_lds)[dsl + 16 * k];

  for (int it = t0; it < t1; ++it) {
    #pragma unroll
    for (int k = 0; k < 8; ++k) {
      int fl = t + 256 * k;
      int r = fl >> 7, c4 = fl & 127;
      ((float4*)x_lds[r])[c4] = pf[k];
    }
    __syncthreads();
    {
      const int n0 = (it + 1) * 16;
      #pragma unroll
      for (int k = 0; k < 8; ++k) {
        int fl = t + 256 * k;
        int r = fl >> 7, c4 = fl & 127;
        int nn = n0 + r;
        pf[k] = (it + 1 < t1 && nn < NN)
                    ? ((const float4*)(Xb + (size_t)nn * DD))[c4]
                    : make_float4(0.f, 0.f, 0.f, 0.f);
      }
    }
    float y = 0.f;
    #pragma unroll
    for (int k = 0; k < 8; ++k) {
      const float4 xv = ((const float4*)x_lds[n])[dsl + 16 * k];
      y += xv.x * preg[k].x + xv.y * preg[k].y + xv.z * preg[k].z + xv.w * preg[k].w;
    }
    #pragma unroll
    for (int mm = 1; mm < 16; mm <<= 1) y += __shfl_xor(y, mm);
    if (dsl == 0) {
      const int nn = it * 16 + n;
      if (nn < NN) {
        bool valid = (mask[(size_t)b * NN + nn] == 0);
        // tanh(y) = 1 - 2/(exp(2y)+1); exp overflow -> inf -> tanh=1 (correct)
        float th = 1.0f - 2.0f / (__expf(2.0f * y) + 1.0f);
        logits[(size_t)b * NN + nn] = valid ? 10.f * th : -3e38f;
      }
    }
    __syncthreads();
  }
}

// ============================================================================
// K5c: scores = softmax over 1000 logits per batch
// ============================================================================
__global__ __launch_bounds__(256) void k_softmax(
    const float* __restrict__ logits, float* __restrict__ out) {
  __shared__ float red[12];
  const int t = threadIdx.x;
  const int b = blockIdx.x;
  const float4* lp = (const float4*)(logits + (size_t)b * NN);
  float4 v = (t < 250) ? lp[t] : make_float4(-3e38f, -3e38f, -3e38f, -3e38f);
  float mx = fmaxf(fmaxf(v.x, v.y), fmaxf(v.z, v.w));
  #pragma unroll
  for (int mm = 1; mm < 64; mm <<= 1) mx = fmaxf(mx, __shfl_xor(mx, mm));
  if ((t & 63) == 0) red[t >> 6] = mx;
  __syncthreads();
  if (t == 0) red[8] = fmaxf(fmaxf(red[0], red[1]), fmaxf(red[2], red[3]));
  __syncthreads();
  const float M = red[8];
  float4 e;
  e.x = (t < 250 && v.x > -1e37f) ? __expf(v.x - M) : 0.f;
  e.y = (t < 250 && v.y > -1e37f) ? __expf(v.y - M) : 0.f;
  e.z = (t < 250 && v.z > -1e37f) ? __expf(v.z - M) : 0.f;
  e.w = (t < 250 && v.w > -1e37f) ? __expf(v.w - M) : 0.f;
  float s = e.x + e.y + e.z + e.w;
  #pragma unroll
  for (int mm = 1; mm < 64; mm <<= 1) s += __shfl_xor(s, mm);
  if ((t & 63) == 0) red[4 + (t >> 6)] = s;
  __syncthreads();
  if (t == 0) red[9] = red[4] + red[5] + red[6] + red[7];
  __syncthreads();
  const float S = red[9];
  const bool uni = (M < -1e37f);  // all masked -> uniform (ref: softmax of zeros)
  const float invS = uni ? 0.f : 1.0f / S;
  if (t < 250) {
    float4 o;
    o.x = uni ? (1.0f / NN) : e.x * invS;
    o.y = uni ? (1.0f / NN) : e.y * invS;
    o.z = uni ? (1.0f / NN) : e.z * invS;
    o.w = uni ? (1.0f / NN) : e.w * invS;
    ((float4*)(out + (size_t)b * NN))[t] = o;
  }
}

// ============================================================================
extern "C" void kernel_launch(void* const* d_in, const int* in_sizes, int n_in,
                              void* d_out, int out_size, void* d_ws, size_t ws_size,
                              hipStream_t stream) {
  const float* X    = (const float*)d_in[0];
  const float* pool = (const float*)d_in[1];
  const float* cap  = (const float*)d_in[2];
  const int*   mask = (const int*)d_in[3];
  const float* Wfc  = (const float*)d_in[4];
  const float* Wfc1 = (const float*)d_in[5];
  const float* Wq   = (const float*)d_in[6];
  const float* Wk   = (const float*)d_in[7];
  const float* Wv   = (const float*)d_in[8];
  const float* Wo   = (const float*)d_in[9];
  const float* Wkp  = (const float*)d_in[10];
  float* out = (float*)d_out;

  float* ws = (float*)d_ws;
  float* state    = ws;                         // 131072
  float* Qt       = state + BB * DD;            // 1048576
  float* ctx_part = Qt + BB * HH * DD;          // 3145728
  float* ml_part  = ctx_part + BB * 3 * HH * DD;// 12288
  float* pre      = ml_part + BB * 3 * HH * 2;  // 131072
  float* mo       = pre + BB * DD;              // 131072
  float* P        = mo + BB * DD;               // 131072
  float* logits   = P + BB * DD;                // 256000   (~19.4 MB total)

  k_state<<<dim3(32, 8), 256, 0, stream>>>(X, pool, cap, Wfc, Wfc1, state);
  k_qt<<<dim3(32, 8), 256, 0, stream>>>(state, Wq, Wk, Qt);
  k_attn<<<dim3(3, BB), 256, 0, stream>>>(X, mask, Qt, ctx_part, ml_part);
  k_pre_merge<<<dim3(32, 8), 256, 0, stream>>>(ctx_part, ml_part, Wv, pre);
  k_mo<<<dim3(32, 8), 256, 0, stream>>>(pre, Wo, mo);
  k_ptr<<<dim3(BB), 256, 0, stream>>>(mo, Wkp, P);
  k_logits<<<dim3(4, BB), 256, 0, stream>>>(X, mask, P, logits);
  k_softmax<<<dim3(BB), 256, 0, stream>>>(logits, out);
}